// Round 4
// baseline (9.757 us; speedup 1.0000x reference)
//
#include <hip/hip_runtime.h>
#include <math.h>

#define NPRIMES 32
#define MAXK    19
#define FLT_BIG 3.402823466e+38f

// exp(-2560*fr^2) as exp2: -2560*log2(e)
#define BETA_C  (-3693.2993047f)
// mask gate: exp(-1600*frac^2) >= 0.99  <=>  frac^2 <= ln(0.99)/(-1600)
#define MASK_THR 6.2815e-6f

// Soft exponent v_p(n), fully collapsed (derivation in rounds 1-3):
//   soft_sort_asc(scores, tau)[-1] == min(scores)   (no pooling at tau=0.01;
//   value path is Sterbenz-exact, bit-identical at the exact zeros that
//   determine the output).
__device__ __forceinline__ float soft_exponent(float n, float p, float lp) {
    // mask gate needs an EXACT frac at divisor points -> one IEEE divide.
    float ratio = n / p;
    float frac  = ratio - rintf(ratio);           // jnp.round = half-even
    bool  maskok = (frac * frac <= MASK_THR);     // == (mask_p >= 0.99) for n>0
    float max_k  = floorf(logf(n) / lp);          // n==0 -> -inf -> gate fails

    // min over 19 gated scores. Zeros come from the k>max_k gate or from
    // exp2 deep-underflow (hundreds of binades of margin) -> robust to the
    // ~1e-7-relative error of v_rcp_f32 iterated reciprocal.
    float rp = __builtin_amdgcn_rcpf(p);
    float r  = n;
    float m  = FLT_BIG;
#pragma unroll
    for (int k = 1; k <= MAXK; ++k) {
        r *= rp;                                  // ~ n / p^k
        float fr = r - rintf(r);
        float mk = exp2f(BETA_C * fr * fr);       // == expf(-2560*fr^2)
        float sc = ((float)k <= max_k) ? mk * (float)k : 0.0f;
        m = fminf(m, sc);
    }
    return (maskok && (max_k >= 1.0f)) ? m : 0.0f;
}

__global__ void softgcd_kernel(const float* __restrict__ n1p,
                               const float* __restrict__ n2p,
                               const float* __restrict__ primes,
                               const float* __restrict__ logp,
                               float* __restrict__ out) {
    const int lane  = threadIdx.x;        // one wave64
    const int pidx  = lane >> 1;          // prime index 0..31
    const int which = lane & 1;           // 0 -> n1, 1 -> n2

    const float p  = primes[pidx];
    const float lp = logp[pidx];
    const float n  = which ? n2p[0] : n1p[0];

    const float e  = soft_exponent(n, p, lp);
    const float ep = __shfl_xor(e, 1, 64);     // partner's exponent

    // pair soft-sort element [0] == max(e1, e2)  (fmin margin 50; exact)
    float contrib = which ? 0.0f : fmaxf(e, ep) * lp;

    // wave64 shuffle reduction
    for (int off = 32; off > 0; off >>= 1)
        contrib += __shfl_down(contrib, off, 64);
    if (lane == 0)
        out[0] = expf(contrib);
}

extern "C" void kernel_launch(void* const* d_in, const int* in_sizes, int n_in,
                              void* d_out, int out_size, void* d_ws, size_t ws_size,
                              hipStream_t stream) {
    const float* n1     = (const float*)d_in[0];
    const float* n2     = (const float*)d_in[1];
    const float* primes = (const float*)d_in[2];
    const float* logp   = (const float*)d_in[3];
    float* out = (float*)d_out;
    softgcd_kernel<<<dim3(1), dim3(64), 0, stream>>>(n1, n2, primes, logp, out);
}